// Round 10
// baseline (262.313 us; speedup 1.0000x reference)
//
#include <hip/hip_runtime.h>

#define NN 50000
#define EE 640000
#define RR 8
#define CAP 64   // per-dst edge capacity; deg ~ Binom(640K, 1/50K), P(deg>=64) ~ 1e-26

typedef __bf16 bf16x8 __attribute__((ext_vector_type(8)));
typedef float  f32x4  __attribute__((ext_vector_type(4)));
typedef const __attribute__((address_space(1))) unsigned int* gas_p;
typedef __attribute__((address_space(3))) unsigned int* las_p;

__device__ __forceinline__ unsigned short f2b(float f) {
  unsigned int u = __float_as_uint(f);
  u += 0x7fffu + ((u >> 16) & 1u);          // round-to-nearest-even
  return (unsigned short)(u >> 16);
}
__device__ __forceinline__ float b2f(unsigned short h) {
  return __uint_as_float(((unsigned int)h) << 16);
}

// per-edge mean scale 1/cnt(d, r) via 3 bitwise ballots: ballot each bit of r,
// AND matching masks, popcount.
__device__ __forceinline__ float edge_scale(unsigned int e, int lane, int deg) {
  unsigned long long valid = __ballot(lane < deg);
  unsigned long long m0 = __ballot((e >> 16) & 1u);
  unsigned long long m1 = __ballot((e >> 17) & 1u);
  unsigned long long m2 = __ballot((e >> 18) & 1u);
  unsigned long long mm = ((e >> 16) & 1u ? m0 : ~m0);
  mm &= ((e >> 17) & 1u ? m1 : ~m1);
  mm &= ((e >> 18) & 1u ? m2 : ~m2);
  mm &= valid;
  return (lane < deg) ? __builtin_amdgcn_rcpf((float)__popcll(mm)) : 0.f;
}

// ---- tiny prologue: build B1^T | build B2^T | zero cursor (~1-2us).
// v10: the x f32->bf16 conversion kernel-work is GONE — layer-1 gemm reads x as
// f32 and converts to bf16 fragments in-register. Cursor zeroing folded here
// (edge atomics run in the NEXT dispatch; kernel boundary orders them) so the
// hipMemsetAsync dispatch is dropped. 6 stream ops -> 5.
#define B1_N (1152 * 128)
#define B2_N (640 * 128)
__global__ void k_prologue(const float* __restrict__ W1, const float* __restrict__ root1,
                           unsigned short* __restrict__ B1T,
                           const float* __restrict__ W2, const float* __restrict__ root2,
                           unsigned short* __restrict__ B2T,
                           int* __restrict__ cursor) {
  int t = blockIdx.x * 256 + threadIdx.x;
  if (t < B1_N) {   // B1^T [1152][128]: rows j = r*128+o (r<8), then root1
    int j = t >> 7, k = t & 127;
    float v = (j < 1024) ? W1[((j >> 7) << 14) + (k << 7) + (j & 127)]
                         : root1[(k << 7) + (j - 1024)];
    B1T[t] = f2b(v);
    return;
  }
  t -= B1_N;
  if (t < B2_N) {   // B2^T [640][128]: rows j = r*64+o (r<8), root2, zero-pad
    int j = t >> 7, k = t & 127;
    float v = 0.0f;
    if (j < 512)      v = W2[((j >> 6) << 13) + (k << 6) + (j & 63)];
    else if (j < 576) v = root2[(k << 6) + (j - 512)];
    B2T[t] = f2b(v);
    return;
  }
  t -= B2_N;
  if (t < NN) cursor[t] = 0;
}

// grid geometry for the fused layer-1 dispatch (r8 best-total configuration)
#define NBG1 1173                 // 391 m-tiles x 3 column-groups
#define NBE  2500                 // 2500 edge blocks x 256 = 640000 edges
#define FSPLIT (3 * NBG1)         // period-3 [gemm, edge, edge] region

// ---- bf16 MFMA GEMM, N-looped, A-in-registers; AF32: A is f32 (x input) and is
// converted to bf16 fragments in-register at block start (~400 VALU ops, amortized
// over 6 subtiles) — removes the separate conversion pass + 38MB of its traffic.
// A-row clamp to M-1: x is an INPUT allocation (25.6MB exact); reading past it
// (old workspace trick) could fault. EDGES=true: edge-list build fused in, r8
// period-3 [gemm,edge,edge] interleave, one edge/thread on 2500 blocks.
// NOTE: __launch_bounds__ MUST stay (256,3). (256,4) caps VGPR at 64 -> compiler
// rematerializes af[4][4] inside the N-loop -> A re-fetched per subtile
// (round-6: FETCH 24->73MB, dur 40->71us). Verify VGPR_Count ~84-96 holds.
template <bool EDGES, bool AF32>
__global__ __launch_bounds__(256, 3) void k_gemm(
    const void* __restrict__ A, const unsigned short* __restrict__ BT,
    unsigned short* __restrict__ Y, float* __restrict__ rootOut,
    const float* __restrict__ bias, int M, int nsplit, int nroot, int nsub,
    const int* __restrict__ srcI, const int* __restrict__ dstI,
    const int* __restrict__ typ, int* __restrict__ cursor,
    unsigned int* __restrict__ entries) {
  __shared__ __align__(16) unsigned short Bs[2][64 * 128];  // 2 x 16KB
  const int tid = threadIdx.x;

  int bg;   // gemm block index
  if (EDGES) {
    const int bid = blockIdx.x;
    int be = -1;
    if (bid < FSPLIT) {
      if (bid % 3 == 0) bg = bid / 3;
      else              be = 2 * (bid / 3) + (bid % 3) - 1;
    } else {
      be = 2 * NBG1 + (bid - FSPLIT);   // tail edge blocks
    }
    if (be >= 0) {
      int e = be * 256 + tid;           // NBE*256 == EE exactly
      if (e < EE) {
        int d = dstI[e], r = typ[e];
        int pos = atomicAdd(&cursor[d], 1);
        if (pos < CAP)
          entries[d * CAP + pos] = (unsigned int)srcI[e] | ((unsigned int)r << 16);
      }
      return;
    }
  } else {
    bg = blockIdx.x;
  }

  const int m0 = (bg % 391) * 128;
  const int n0g = (bg / 391) * nsub * 64;
  const int lane = tid & 63;
  const int wave = tid >> 6;
  const int wm = (wave >> 1) << 6;   // M-half of wave: 0 / 64
  const int wn = (wave & 1) << 5;    // N-half of wave: 0 / 32 (within 64-col sub-tile)
  const int l15 = lane & 15;
  const int quad = lane >> 4;

  // ---- stage B sub-tile 0 into LDS (XOR-swizzled source; frag reads conflict-free) ----
  {
    const unsigned short* Gb = BT + (size_t)n0g * 128;
#pragma unroll
    for (int c = 0; c < 4; ++c) {
      int L = tid + c * 256;
      int r = L >> 4, c16 = L & 15;
      int j = c16 ^ (r & 15);
      __builtin_amdgcn_global_load_lds(
          (gas_p)(const void*)(Gb + (size_t)r * 128 + j * 8),
          (las_p)(void*)(Bs[0] + r * 128 + c16 * 8), 16, 0, 0);
    }
  }

  // ---- A fragments straight to registers (row clamped to M-1) ----
  bf16x8 af[4][4];
  if (AF32) {
    const float* Af = (const float*)A;
#pragma unroll
    for (int kk = 0; kk < 4; ++kk)
#pragma unroll
      for (int i = 0; i < 4; ++i) {
        int rA = m0 + wm + i * 16 + l15;
        if (rA > M - 1) rA = M - 1;
        const float* p = Af + (size_t)rA * 128 + (kk * 4 + quad) * 8;
        float4 q0 = *reinterpret_cast<const float4*>(p);
        float4 q1 = *reinterpret_cast<const float4*>(p + 4);
        uint4 u;
        u.x = (unsigned int)f2b(q0.x) | ((unsigned int)f2b(q0.y) << 16);
        u.y = (unsigned int)f2b(q0.z) | ((unsigned int)f2b(q0.w) << 16);
        u.z = (unsigned int)f2b(q1.x) | ((unsigned int)f2b(q1.y) << 16);
        u.w = (unsigned int)f2b(q1.z) | ((unsigned int)f2b(q1.w) << 16);
        af[kk][i] = *reinterpret_cast<bf16x8*>(&u);
      }
  } else {
    const unsigned short* Ab = (const unsigned short*)A;
#pragma unroll
    for (int kk = 0; kk < 4; ++kk)
#pragma unroll
      for (int i = 0; i < 4; ++i) {
        int rA = m0 + wm + i * 16 + l15;
        if (rA > M - 1) rA = M - 1;
        af[kk][i] = *reinterpret_cast<const bf16x8*>(
            Ab + (size_t)rA * 128 + (kk * 4 + quad) * 8);
      }
  }

  __syncthreads();   // B0 staged (vmcnt(0) also covers A loads)

  // transpose-store geometry: lane t -> row tr, 8-col chunk tc
  const int tr = lane >> 2;                   // 0..15
  const int tc = lane & 3;                    // 0..3
  const int sl0 = ((tc & 1) << 1) * 16 + tr;  // source lane, cols 0..3 of chunk
  const int sl1 = sl0 + 16;                   // source lane, cols 4..7 of chunk
  const bool thi = (tc & 2) != 0;             // chunk comes from j=1 fragment

  int buf = 0;
  for (int s = 0; s < nsub; ++s) {
    if (s + 1 < nsub) {
      const unsigned short* Gb = BT + (size_t)(n0g + (s + 1) * 64) * 128;
      unsigned short* Lb = Bs[buf ^ 1];
#pragma unroll
      for (int c = 0; c < 4; ++c) {
        int L = tid + c * 256;
        int r = L >> 4, c16 = L & 15;
        int j = c16 ^ (r & 15);
        __builtin_amdgcn_global_load_lds(
            (gas_p)(const void*)(Gb + (size_t)r * 128 + j * 8),
            (las_p)(void*)(Lb + r * 128 + c16 * 8), 16, 0, 0);
      }
    }

    f32x4 acc[4][2] = {};
    const unsigned short* Bc = Bs[buf];
#pragma unroll
    for (int kk = 0; kk < 4; ++kk) {
      const int sw = ((kk * 4 + quad) ^ l15) * 8;
      bf16x8 bfr[2];
#pragma unroll
      for (int j = 0; j < 2; ++j)
        bfr[j] = *reinterpret_cast<const bf16x8*>(&Bc[(wn + j * 16 + l15) * 128 + sw]);
#pragma unroll
      for (int i = 0; i < 4; ++i)
#pragma unroll
        for (int j = 0; j < 2; ++j)   // swapped operands: lane -> row m, quad*4+r -> col n
          acc[i][j] = __builtin_amdgcn_mfma_f32_16x16x32_bf16(bfr[j], af[kk][i], acc[i][j], 0, 0, 0);
    }
    __syncthreads();   // reads of Bs[buf] done; prefetch of Bs[buf^1] complete

    const int scol = n0g + s * 64;
    if (scol >= nsplit) {
      // root sub-tile: f32 + bias, direct float4 stores
#pragma unroll
      for (int i = 0; i < 4; ++i) {
        const int m = wm + i * 16 + l15;
        if (m0 + m >= M) continue;
#pragma unroll
        for (int j = 0; j < 2; ++j) {
          const int col = scol + wn + j * 16 + quad * 4 - nsplit;
          if (col < nroot) {
            float4 b4 = *reinterpret_cast<const float4*>(&bias[col]);
            float4 v = make_float4(acc[i][j][0] + b4.x, acc[i][j][1] + b4.y,
                                   acc[i][j][2] + b4.z, acc[i][j][3] + b4.w);
            *reinterpret_cast<float4*>(&rootOut[(size_t)(m0 + m) * nroot + col]) = v;
          }
        }
      }
    } else {
      // Y sub-tile: pack bf16x4, shfl-transpose, full-wave uint4 stores
#pragma unroll
      for (int i = 0; i < 4; ++i) {
        uint2 pk0, pk1;
        pk0.x = (unsigned int)f2b(acc[i][0][0]) | ((unsigned int)f2b(acc[i][0][1]) << 16);
        pk0.y = (unsigned int)f2b(acc[i][0][2]) | ((unsigned int)f2b(acc[i][0][3]) << 16);
        pk1.x = (unsigned int)f2b(acc[i][1][0]) | ((unsigned int)f2b(acc[i][1][1]) << 16);
        pk1.y = (unsigned int)f2b(acc[i][1][2]) | ((unsigned int)f2b(acc[i][1][3]) << 16);
        unsigned int a0x = __shfl(pk0.x, sl0, 64), a0y = __shfl(pk0.y, sl0, 64);
        unsigned int a1x = __shfl(pk1.x, sl0, 64), a1y = __shfl(pk1.y, sl0, 64);
        unsigned int b0x = __shfl(pk0.x, sl1, 64), b0y = __shfl(pk0.y, sl1, 64);
        unsigned int b1x = __shfl(pk1.x, sl1, 64), b1y = __shfl(pk1.y, sl1, 64);
        uint4 o;
        o.x = thi ? a1x : a0x;
        o.y = thi ? a1y : a0y;
        o.z = thi ? b1x : b0x;
        o.w = thi ? b1y : b0y;
        const int m = wm + i * 16 + tr;
        if (m0 + m < M)
          *reinterpret_cast<uint4*>(&Y[(size_t)(m0 + m) * nsplit + scol + wn + tc * 8]) = o;
      }
    }
    buf ^= 1;
  }
}

#define ACC8(pk, s)                                          \
  a[0] += b2f((unsigned short)pk.x) * s;                     \
  a[1] += __uint_as_float(pk.x & 0xffff0000u) * s;           \
  a[2] += b2f((unsigned short)pk.y) * s;                     \
  a[3] += __uint_as_float(pk.y & 0xffff0000u) * s;           \
  a[4] += b2f((unsigned short)pk.z) * s;                     \
  a[5] += __uint_as_float(pk.z & 0xffff0000u) * s;           \
  a[6] += b2f((unsigned short)pk.w) * s;                     \
  a[7] += __uint_as_float(pk.w & 0xffff0000u) * s;

// ---- layer-1 pull-aggregate: one wave per dst, 128 feats.
// 16 edge-slots/iter (4x uint4 in flight, T=1 for ~85% of dsts), 3-ballot counts,
// hpre hoisted above the gather loop. Ghost slots read row 0, contribute nothing.
__global__ void k_agg1(const unsigned int* __restrict__ entries,
                       const int* __restrict__ cursor,
                       const unsigned short* __restrict__ y,
                       const float* __restrict__ hpre,
                       unsigned int* __restrict__ hbf) {
  const int d = blockIdx.x * 4 + (threadIdx.x >> 6);   // NN % 4 == 0
  const int lane = threadIdx.x & 63;
  int deg = cursor[d];
  if (deg > CAP) deg = CAP;
  unsigned int e = (lane < deg) ? entries[d * CAP + lane] : 0u;
  float sc = edge_scale(e, lane, deg);

  const int g = lane >> 4;    // edge slot within 16-slot pack
  const int l16 = lane & 15;  // feature slice: feats 8*l16 .. 8*l16+7

  float4 h0, h1;
  if (g == 0) {
    const float4* hp = reinterpret_cast<const float4*>(hpre) + (size_t)d * 32 + l16 * 2;
    h0 = hp[0];
    h1 = hp[1];
  }

  float a[8] = {};
  const int T = (deg + 15) >> 4;   // 16 edges per iteration (4x uint4 loads)
  for (int t = 0; t < T; ++t) {
    const int base = t * 16 + g;
    unsigned int e0 = __shfl(e, base, 64);       float s0 = __shfl(sc, base, 64);
    unsigned int e1 = __shfl(e, base + 4, 64);   float s1 = __shfl(sc, base + 4, 64);
    unsigned int e2 = __shfl(e, base + 8, 64);   float s2 = __shfl(sc, base + 8, 64);
    unsigned int e3 = __shfl(e, base + 12, 64);  float s3 = __shfl(sc, base + 12, 64);
    uint4 p0 = *reinterpret_cast<const uint4*>(
        y + (((size_t)(e0 & 0xffffu)) << 10) + (((e0 >> 16) & 7u) << 7) + (l16 << 3));
    uint4 p1 = *reinterpret_cast<const uint4*>(
        y + (((size_t)(e1 & 0xffffu)) << 10) + (((e1 >> 16) & 7u) << 7) + (l16 << 3));
    uint4 p2 = *reinterpret_cast<const uint4*>(
        y + (((size_t)(e2 & 0xffffu)) << 10) + (((e2 >> 16) & 7u) << 7) + (l16 << 3));
    uint4 p3 = *reinterpret_cast<const uint4*>(
        y + (((size_t)(e3 & 0xffffu)) << 10) + (((e3 >> 16) & 7u) << 7) + (l16 << 3));
    ACC8(p0, s0);
    ACC8(p1, s1);
    ACC8(p2, s2);
    ACC8(p3, s3);
  }
#pragma unroll
  for (int j = 0; j < 8; ++j) {
    a[j] += __shfl_xor(a[j], 16, 64);
    a[j] += __shfl_xor(a[j], 32, 64);
  }
  if (g == 0) {
    float v0 = fmaxf(a[0] + h0.x, 0.f), v1 = fmaxf(a[1] + h0.y, 0.f);
    float v2 = fmaxf(a[2] + h0.z, 0.f), v3 = fmaxf(a[3] + h0.w, 0.f);
    float v4 = fmaxf(a[4] + h1.x, 0.f), v5 = fmaxf(a[5] + h1.y, 0.f);
    float v6 = fmaxf(a[6] + h1.z, 0.f), v7 = fmaxf(a[7] + h1.w, 0.f);
    uint4 o;
    o.x = (unsigned int)f2b(v0) | ((unsigned int)f2b(v1) << 16);
    o.y = (unsigned int)f2b(v2) | ((unsigned int)f2b(v3) << 16);
    o.z = (unsigned int)f2b(v4) | ((unsigned int)f2b(v5) << 16);
    o.w = (unsigned int)f2b(v6) | ((unsigned int)f2b(v7) << 16);
    reinterpret_cast<uint4*>(hbf)[(size_t)d * 16 + l16] = o;
  }
}

// ---- layer-2 pull-aggregate + classifier: one wave per dst, 64 feats.
// 32 edge-slots/iter (T=1 for ~all dsts), 3-ballot counts, hoisted hpre.
__global__ void k_agg2(const unsigned int* __restrict__ entries,
                       const int* __restrict__ cursor,
                       const unsigned short* __restrict__ y,
                       const float* __restrict__ hpre,
                       const float* __restrict__ Wc, const float* __restrict__ bc,
                       float* __restrict__ out) {
  const int d = blockIdx.x * 4 + (threadIdx.x >> 6);
  const int lane = threadIdx.x & 63;
  int deg = cursor[d];
  if (deg > CAP) deg = CAP;
  unsigned int e = (lane < deg) ? entries[d * CAP + lane] : 0u;
  float sc = edge_scale(e, lane, deg);

  const int g = lane >> 3;   // edge slot within 32-slot pack
  const int l8 = lane & 7;   // feature slice: feats 8*l8 .. 8*l8+7

  const float4* hp = reinterpret_cast<const float4*>(hpre) + (size_t)d * 16 + l8 * 2;
  float4 h0 = hp[0];
  float4 h1 = hp[1];

  float a[8] = {};
  const int T = (deg + 31) >> 5;   // 32 edges per iteration (4x uint4 loads)
  for (int t = 0; t < T; ++t) {
    const int base = t * 32 + g;
    unsigned int e0 = __shfl(e, base, 64);       float s0 = __shfl(sc, base, 64);
    unsigned int e1 = __shfl(e, base + 8, 64);   float s1 = __shfl(sc, base + 8, 64);
    unsigned int e2 = __shfl(e, base + 16, 64);  float s2 = __shfl(sc, base + 16, 64);
    unsigned int e3 = __shfl(e, base + 24, 64);  float s3 = __shfl(sc, base + 24, 64);
    uint4 p0 = *reinterpret_cast<const uint4*>(
        y + (((size_t)(e0 & 0xffffu)) << 9) + (((e0 >> 16) & 7u) << 6) + (l8 << 3));
    uint4 p1 = *reinterpret_cast<const uint4*>(
        y + (((size_t)(e1 & 0xffffu)) << 9) + (((e1 >> 16) & 7u) << 6) + (l8 << 3));
    uint4 p2 = *reinterpret_cast<const uint4*>(
        y + (((size_t)(e2 & 0xffffu)) << 9) + (((e2 >> 16) & 7u) << 6) + (l8 << 3));
    uint4 p3 = *reinterpret_cast<const uint4*>(
        y + (((size_t)(e3 & 0xffffu)) << 9) + (((e3 >> 16) & 7u) << 6) + (l8 << 3));
    ACC8(p0, s0);
    ACC8(p1, s1);
    ACC8(p2, s2);
    ACC8(p3, s3);
  }
#pragma unroll
  for (int j = 0; j < 8; ++j) {
    a[j] += __shfl_xor(a[j], 8, 64);
    a[j] += __shfl_xor(a[j], 16, 64);
    a[j] += __shfl_xor(a[j], 32, 64);
  }
  float v0 = fmaxf(a[0] + h0.x, 0.f), v1 = fmaxf(a[1] + h0.y, 0.f);
  float v2 = fmaxf(a[2] + h0.z, 0.f), v3 = fmaxf(a[3] + h0.w, 0.f);
  float v4 = fmaxf(a[4] + h1.x, 0.f), v5 = fmaxf(a[5] + h1.y, 0.f);
  float v6 = fmaxf(a[6] + h1.z, 0.f), v7 = fmaxf(a[7] + h1.w, 0.f);
  const float4* wc4 = reinterpret_cast<const float4*>(Wc) + l8 * 4;
  float4 w0 = wc4[0], w1 = wc4[1], w2 = wc4[2], w3 = wc4[3];
  float p0 = v0 * w0.x + v1 * w0.z + v2 * w1.x + v3 * w1.z
           + v4 * w2.x + v5 * w2.z + v6 * w3.x + v7 * w3.z;
  float p1 = v0 * w0.y + v1 * w0.w + v2 * w1.y + v3 * w1.w
           + v4 * w2.y + v5 * w2.w + v6 * w3.y + v7 * w3.w;
  p0 += __shfl_xor(p0, 1, 64); p1 += __shfl_xor(p1, 1, 64);
  p0 += __shfl_xor(p0, 2, 64); p1 += __shfl_xor(p1, 2, 64);
  p0 += __shfl_xor(p0, 4, 64); p1 += __shfl_xor(p1, 4, 64);
  if (lane == 0) {
    out[d * 2 + 0] = p0 + bc[0];
    out[d * 2 + 1] = p1 + bc[1];
  }
}

extern "C" void kernel_launch(void* const* d_in, const int* in_sizes, int n_in,
                              void* d_out, int out_size, void* d_ws, size_t ws_size,
                              hipStream_t stream) {
  const float* x     = (const float*)d_in[0];
  const int*   ei    = (const int*)d_in[1];
  const int*   et    = (const int*)d_in[2];
  const float* W1    = (const float*)d_in[3];
  const float* root1 = (const float*)d_in[4];
  const float* b1    = (const float*)d_in[5];
  const float* W2    = (const float*)d_in[6];
  const float* root2 = (const float*)d_in[7];
  const float* b2    = (const float*)d_in[8];
  const float* Wc    = (const float*)d_in[9];
  const float* bc    = (const float*)d_in[10];
  const int* srcI = ei;        // edge_index[0]
  const int* dstI = ei + EE;   // edge_index[1]

  char* ws = (char*)d_ws;
  unsigned int*   hbf     = (unsigned int*)(ws);               // 12,800,000 B (layer-1 agg out)
  unsigned short* B1T     = (unsigned short*)(ws + 12800000);  //    294,912 B
  unsigned short* B2T     = (unsigned short*)(ws + 13094912);  //    163,840 B
  int*            cursor  = (int*)(ws + 13258752);             //    200,000 B
  unsigned int*   entries = (unsigned int*)(ws + 13458752);    // 12,800,000 B (50000*64*4)
  float*          hpre    = (float*)(ws + 26258752);           // 25,600,000 B (reused layer 2)
  unsigned short* y1      = (unsigned short*)(ws + 51858752);  // 102,400,000 B
  unsigned short* y2      = y1;                                // alias (y1 dead after agg1)
  // total: 154,258,752 B

  // tiny prologue: B1^T + B2^T + cursor zero (one dispatch; no memset, no conv)
  const int PRO_N = B1_N + B2_N + NN;
  k_prologue<<<(PRO_N + 255) / 256, 256, 0, stream>>>(W1, root1, B1T,
                                                      W2, root2, B2T, cursor);

  // layer 1 (fused): y1 = x @ [W1_0..W1_7] (bf16; x read as f32, converted
  // in-register), hpre = x @ root1 + b1 (f32), PLUS edge-list build on 2500
  // interleaved edge blocks (r8 period-3 geometry).
  k_gemm<true, true><<<dim3(NBG1 + NBE), 256, 0, stream>>>(
      (const void*)x, B1T, y1, hpre, b1, NN, 1024, 128, 6,
      srcI, dstI, et, cursor, entries);
  k_agg1<<<NN / 4, 256, 0, stream>>>(entries, cursor, y1, hpre, hbf);

  // layer 2: y2 = hbf @ [W2_0..W2_7] (bf16), hpre = hbf @ root2 + b2 (f32)
  k_gemm<false, false><<<dim3(391 * 2), 256, 0, stream>>>(
      (const void*)hbf, B2T, y2, hpre, b2, NN, 512, 64, 5,
      nullptr, nullptr, nullptr, nullptr, nullptr);
  k_agg2<<<NN / 4, 256, 0, stream>>>(entries, cursor, y2, hpre, Wc, bc, (float*)d_out);
}

// Round 11
// 228.632 us; speedup vs baseline: 1.1473x; 1.1473x over previous
//
#include <hip/hip_runtime.h>

#define NN 50000
#define EE 640000
#define RR 8
#define CAP 48        // per-dst edge capacity; deg ~ Binom(640K,1/50K) mean 12.8, P(deg>48)~3e-8
#define CSTRIDE 16    // cursor padded to 1 counter per 64B line (atomic line-contention fix)

typedef __bf16 bf16x8 __attribute__((ext_vector_type(8)));
typedef float  f32x4  __attribute__((ext_vector_type(4)));
typedef const __attribute__((address_space(1))) unsigned int* gas_p;
typedef __attribute__((address_space(3))) unsigned int* las_p;

__device__ __forceinline__ unsigned short f2b(float f) {
  unsigned int u = __float_as_uint(f);
  u += 0x7fffu + ((u >> 16) & 1u);          // round-to-nearest-even
  return (unsigned short)(u >> 16);
}
__device__ __forceinline__ float b2f(unsigned short h) {
  return __uint_as_float(((unsigned int)h) << 16);
}

// per-edge mean scale 1/cnt(d, r) via 3 bitwise ballots: ballot each bit of r,
// AND matching masks, popcount.
__device__ __forceinline__ float edge_scale(unsigned int e, int lane, int deg) {
  unsigned long long valid = __ballot(lane < deg);
  unsigned long long m0 = __ballot((e >> 16) & 1u);
  unsigned long long m1 = __ballot((e >> 17) & 1u);
  unsigned long long m2 = __ballot((e >> 18) & 1u);
  unsigned long long mm = ((e >> 16) & 1u ? m0 : ~m0);
  mm &= ((e >> 17) & 1u ? m1 : ~m1);
  mm &= ((e >> 18) & 1u ? m2 : ~m2);
  mm &= valid;
  return (lane < deg) ? __builtin_amdgcn_rcpf((float)__popcll(mm)) : 0.f;
}

// ---- prologue: x f32->bf16 | build B1^T | build B2^T | zero padded cursor.
// AF32 reverted (r10: FETCH 24->43MB, fused +6us — in-gemm conversion is a net
// loss vs a streaming conv pass). Cursor zeroing here (edges run next dispatch).
#define CONV_N 1600000            // float4 count for x (50000*128/4)
#define B1_N (1152 * 128)
#define B2_N (640 * 128)
__global__ void k_prologue(const float* __restrict__ x, unsigned short* __restrict__ xb,
                           const float* __restrict__ W1, const float* __restrict__ root1,
                           unsigned short* __restrict__ B1T,
                           const float* __restrict__ W2, const float* __restrict__ root2,
                           unsigned short* __restrict__ B2T,
                           int* __restrict__ cursor) {
  int t = blockIdx.x * 256 + threadIdx.x;
  if (t < CONV_N) {
    float4 v = reinterpret_cast<const float4*>(x)[t];
    ushort4 o = make_ushort4(f2b(v.x), f2b(v.y), f2b(v.z), f2b(v.w));
    reinterpret_cast<ushort4*>(xb)[t] = o;
    return;
  }
  t -= CONV_N;
  if (t < B1_N) {   // B1^T [1152][128]: rows j = r*128+o (r<8), then root1
    int j = t >> 7, k = t & 127;
    float v = (j < 1024) ? W1[((j >> 7) << 14) + (k << 7) + (j & 127)]
                         : root1[(k << 7) + (j - 1024)];
    B1T[t] = f2b(v);
    return;
  }
  t -= B1_N;
  if (t < B2_N) {   // B2^T [640][128]: rows j = r*64+o (r<8), root2, zero-pad
    int j = t >> 7, k = t & 127;
    float v = 0.0f;
    if (j < 512)      v = W2[((j >> 6) << 13) + (k << 6) + (j & 63)];
    else if (j < 576) v = root2[(k << 6) + (j - 512)];
    B2T[t] = f2b(v);
    return;
  }
  t -= B2_N;
  if (t < NN) cursor[t * CSTRIDE] = 0;
}

// grid geometry for the fused layer-1 dispatch (r8 best-total configuration)
#define NBG1 1173                 // 391 m-tiles x 3 column-groups
#define NBE  2500                 // 2500 edge blocks x 256 = 640000 edges
#define FSPLIT (3 * NBG1)         // period-3 [gemm, edge, edge] region

// ---- bf16 MFMA GEMM, N-looped, A-in-registers; EDGES=true fuses the edge-list
// build (r8 period-3 interleave, one edge/thread). v11: cursor atomics hit
// 64B-padded counters (cursor[d*16]) — tests the line-serialization theory for
// why the edge pass ran at 45us with 1.8% VALU / 16% HBM (16 counters/line x
// 12.8 edges/dst = ~205 contenders per L2 line before padding).
// NOTE: __launch_bounds__ MUST stay (256,3). (256,4) caps VGPR at 64 -> compiler
// rematerializes af[4][4] inside the N-loop -> A re-fetched per subtile
// (round-6: FETCH 24->73MB, dur 40->71us). Verify VGPR_Count ~84 holds.
template <bool EDGES>
__global__ __launch_bounds__(256, 3) void k_gemm(
    const unsigned short* __restrict__ A, const unsigned short* __restrict__ BT,
    unsigned short* __restrict__ Y, float* __restrict__ rootOut,
    const float* __restrict__ bias, int M, int nsplit, int nroot, int nsub,
    const int* __restrict__ srcI, const int* __restrict__ dstI,
    const int* __restrict__ typ, int* __restrict__ cursor,
    unsigned int* __restrict__ entries) {
  __shared__ __align__(16) unsigned short Bs[2][64 * 128];  // 2 x 16KB
  const int tid = threadIdx.x;

  int bg;   // gemm block index
  if (EDGES) {
    const int bid = blockIdx.x;
    int be = -1;
    if (bid < FSPLIT) {
      if (bid % 3 == 0) bg = bid / 3;
      else              be = 2 * (bid / 3) + (bid % 3) - 1;
    } else {
      be = 2 * NBG1 + (bid - FSPLIT);   // tail edge blocks
    }
    if (be >= 0) {
      int e = be * 256 + tid;           // NBE*256 == EE exactly
      if (e < EE) {
        int d = dstI[e], r = typ[e];
        int pos = atomicAdd(&cursor[d * CSTRIDE], 1);
        if (pos < CAP)
          entries[d * CAP + pos] = (unsigned int)srcI[e] | ((unsigned int)r << 16);
      }
      return;
    }
  } else {
    bg = blockIdx.x;
  }

  const int m0 = (bg % 391) * 128;
  const int n0g = (bg / 391) * nsub * 64;
  const int lane = tid & 63;
  const int wave = tid >> 6;
  const int wm = (wave >> 1) << 6;   // M-half of wave: 0 / 64
  const int wn = (wave & 1) << 5;    // N-half of wave: 0 / 32 (within 64-col sub-tile)
  const int l15 = lane & 15;
  const int quad = lane >> 4;

  // ---- stage B sub-tile 0 into LDS (XOR-swizzled source; frag reads conflict-free) ----
  {
    const unsigned short* Gb = BT + (size_t)n0g * 128;
#pragma unroll
    for (int c = 0; c < 4; ++c) {
      int L = tid + c * 256;
      int r = L >> 4, c16 = L & 15;
      int j = c16 ^ (r & 15);
      __builtin_amdgcn_global_load_lds(
          (gas_p)(const void*)(Gb + (size_t)r * 128 + j * 8),
          (las_p)(void*)(Bs[0] + r * 128 + c16 * 8), 16, 0, 0);
    }
  }

  // ---- A fragments straight to registers (row clamped to M-1; xb is exactly
  // 12.8MB so no overread past the workspace region) ----
  bf16x8 af[4][4];
#pragma unroll
  for (int kk = 0; kk < 4; ++kk)
#pragma unroll
    for (int i = 0; i < 4; ++i) {
      int rA = m0 + wm + i * 16 + l15;
      if (rA > M - 1) rA = M - 1;
      af[kk][i] = *reinterpret_cast<const bf16x8*>(
          A + (size_t)rA * 128 + (kk * 4 + quad) * 8);
    }

  __syncthreads();   // B0 staged (vmcnt(0) also covers af loads)

  // transpose-store geometry: lane t -> row tr, 8-col chunk tc
  const int tr = lane >> 2;                   // 0..15
  const int tc = lane & 3;                    // 0..3
  const int sl0 = ((tc & 1) << 1) * 16 + tr;  // source lane, cols 0..3 of chunk
  const int sl1 = sl0 + 16;                   // source lane, cols 4..7 of chunk
  const bool thi = (tc & 2) != 0;             // chunk comes from j=1 fragment

  int buf = 0;
  for (int s = 0; s < nsub; ++s) {
    if (s + 1 < nsub) {
      const unsigned short* Gb = BT + (size_t)(n0g + (s + 1) * 64) * 128;
      unsigned short* Lb = Bs[buf ^ 1];
#pragma unroll
      for (int c = 0; c < 4; ++c) {
        int L = tid + c * 256;
        int r = L >> 4, c16 = L & 15;
        int j = c16 ^ (r & 15);
        __builtin_amdgcn_global_load_lds(
            (gas_p)(const void*)(Gb + (size_t)r * 128 + j * 8),
            (las_p)(void*)(Lb + r * 128 + c16 * 8), 16, 0, 0);
      }
    }

    f32x4 acc[4][2] = {};
    const unsigned short* Bc = Bs[buf];
#pragma unroll
    for (int kk = 0; kk < 4; ++kk) {
      const int sw = ((kk * 4 + quad) ^ l15) * 8;
      bf16x8 bfr[2];
#pragma unroll
      for (int j = 0; j < 2; ++j)
        bfr[j] = *reinterpret_cast<const bf16x8*>(&Bc[(wn + j * 16 + l15) * 128 + sw]);
#pragma unroll
      for (int i = 0; i < 4; ++i)
#pragma unroll
        for (int j = 0; j < 2; ++j)   // swapped operands: lane -> row m, quad*4+r -> col n
          acc[i][j] = __builtin_amdgcn_mfma_f32_16x16x32_bf16(bfr[j], af[kk][i], acc[i][j], 0, 0, 0);
    }
    __syncthreads();   // reads of Bs[buf] done; prefetch of Bs[buf^1] complete

    const int scol = n0g + s * 64;
    if (scol >= nsplit) {
      // root sub-tile: f32 + bias, direct float4 stores
#pragma unroll
      for (int i = 0; i < 4; ++i) {
        const int m = wm + i * 16 + l15;
        if (m0 + m >= M) continue;
#pragma unroll
        for (int j = 0; j < 2; ++j) {
          const int col = scol + wn + j * 16 + quad * 4 - nsplit;
          if (col < nroot) {
            float4 b4 = *reinterpret_cast<const float4*>(&bias[col]);
            float4 v = make_float4(acc[i][j][0] + b4.x, acc[i][j][1] + b4.y,
                                   acc[i][j][2] + b4.z, acc[i][j][3] + b4.w);
            *reinterpret_cast<float4*>(&rootOut[(size_t)(m0 + m) * nroot + col]) = v;
          }
        }
      }
    } else {
      // Y sub-tile: pack bf16x4, shfl-transpose, full-wave uint4 stores
#pragma unroll
      for (int i = 0; i < 4; ++i) {
        uint2 pk0, pk1;
        pk0.x = (unsigned int)f2b(acc[i][0][0]) | ((unsigned int)f2b(acc[i][0][1]) << 16);
        pk0.y = (unsigned int)f2b(acc[i][0][2]) | ((unsigned int)f2b(acc[i][0][3]) << 16);
        pk1.x = (unsigned int)f2b(acc[i][1][0]) | ((unsigned int)f2b(acc[i][1][1]) << 16);
        pk1.y = (unsigned int)f2b(acc[i][1][2]) | ((unsigned int)f2b(acc[i][1][3]) << 16);
        unsigned int a0x = __shfl(pk0.x, sl0, 64), a0y = __shfl(pk0.y, sl0, 64);
        unsigned int a1x = __shfl(pk1.x, sl0, 64), a1y = __shfl(pk1.y, sl0, 64);
        unsigned int b0x = __shfl(pk0.x, sl1, 64), b0y = __shfl(pk0.y, sl1, 64);
        unsigned int b1x = __shfl(pk1.x, sl1, 64), b1y = __shfl(pk1.y, sl1, 64);
        uint4 o;
        o.x = thi ? a1x : a0x;
        o.y = thi ? a1y : a0y;
        o.z = thi ? b1x : b0x;
        o.w = thi ? b1y : b0y;
        const int m = wm + i * 16 + tr;
        if (m0 + m < M)
          *reinterpret_cast<uint4*>(&Y[(size_t)(m0 + m) * nsplit + scol + wn + tc * 8]) = o;
      }
    }
    buf ^= 1;
  }
}

#define ACC8(pk, s)                                          \
  a[0] += b2f((unsigned short)pk.x) * s;                     \
  a[1] += __uint_as_float(pk.x & 0xffff0000u) * s;           \
  a[2] += b2f((unsigned short)pk.y) * s;                     \
  a[3] += __uint_as_float(pk.y & 0xffff0000u) * s;           \
  a[4] += b2f((unsigned short)pk.z) * s;                     \
  a[5] += __uint_as_float(pk.z & 0xffff0000u) * s;           \
  a[6] += b2f((unsigned short)pk.w) * s;                     \
  a[7] += __uint_as_float(pk.w & 0xffff0000u) * s;

// ---- layer-1 pull-aggregate: one wave per dst, 128 feats.
// 16 edge-slots/iter (4x uint4 in flight), 3-ballot counts, hoisted hpre.
__global__ void k_agg1(const unsigned int* __restrict__ entries,
                       const int* __restrict__ cursor,
                       const unsigned short* __restrict__ y,
                       const float* __restrict__ hpre,
                       unsigned int* __restrict__ hbf) {
  const int d = blockIdx.x * 4 + (threadIdx.x >> 6);   // NN % 4 == 0
  const int lane = threadIdx.x & 63;
  int deg = cursor[d * CSTRIDE];
  if (deg > CAP) deg = CAP;
  unsigned int e = (lane < deg) ? entries[d * CAP + lane] : 0u;
  float sc = edge_scale(e, lane, deg);

  const int g = lane >> 4;    // edge slot within 16-slot pack
  const int l16 = lane & 15;  // feature slice: feats 8*l16 .. 8*l16+7

  float4 h0, h1;
  if (g == 0) {
    const float4* hp = reinterpret_cast<const float4*>(hpre) + (size_t)d * 32 + l16 * 2;
    h0 = hp[0];
    h1 = hp[1];
  }

  float a[8] = {};
  const int T = (deg + 15) >> 4;   // 16 edges per iteration (4x uint4 loads)
  for (int t = 0; t < T; ++t) {
    const int base = t * 16 + g;
    unsigned int e0 = __shfl(e, base, 64);       float s0 = __shfl(sc, base, 64);
    unsigned int e1 = __shfl(e, base + 4, 64);   float s1 = __shfl(sc, base + 4, 64);
    unsigned int e2 = __shfl(e, base + 8, 64);   float s2 = __shfl(sc, base + 8, 64);
    unsigned int e3 = __shfl(e, base + 12, 64);  float s3 = __shfl(sc, base + 12, 64);
    uint4 p0 = *reinterpret_cast<const uint4*>(
        y + (((size_t)(e0 & 0xffffu)) << 10) + (((e0 >> 16) & 7u) << 7) + (l16 << 3));
    uint4 p1 = *reinterpret_cast<const uint4*>(
        y + (((size_t)(e1 & 0xffffu)) << 10) + (((e1 >> 16) & 7u) << 7) + (l16 << 3));
    uint4 p2 = *reinterpret_cast<const uint4*>(
        y + (((size_t)(e2 & 0xffffu)) << 10) + (((e2 >> 16) & 7u) << 7) + (l16 << 3));
    uint4 p3 = *reinterpret_cast<const uint4*>(
        y + (((size_t)(e3 & 0xffffu)) << 10) + (((e3 >> 16) & 7u) << 7) + (l16 << 3));
    ACC8(p0, s0);
    ACC8(p1, s1);
    ACC8(p2, s2);
    ACC8(p3, s3);
  }
#pragma unroll
  for (int j = 0; j < 8; ++j) {
    a[j] += __shfl_xor(a[j], 16, 64);
    a[j] += __shfl_xor(a[j], 32, 64);
  }
  if (g == 0) {
    float v0 = fmaxf(a[0] + h0.x, 0.f), v1 = fmaxf(a[1] + h0.y, 0.f);
    float v2 = fmaxf(a[2] + h0.z, 0.f), v3 = fmaxf(a[3] + h0.w, 0.f);
    float v4 = fmaxf(a[4] + h1.x, 0.f), v5 = fmaxf(a[5] + h1.y, 0.f);
    float v6 = fmaxf(a[6] + h1.z, 0.f), v7 = fmaxf(a[7] + h1.w, 0.f);
    uint4 o;
    o.x = (unsigned int)f2b(v0) | ((unsigned int)f2b(v1) << 16);
    o.y = (unsigned int)f2b(v2) | ((unsigned int)f2b(v3) << 16);
    o.z = (unsigned int)f2b(v4) | ((unsigned int)f2b(v5) << 16);
    o.w = (unsigned int)f2b(v6) | ((unsigned int)f2b(v7) << 16);
    reinterpret_cast<uint4*>(hbf)[(size_t)d * 16 + l16] = o;
  }
}

// ---- layer-2 pull-aggregate + classifier: one wave per dst, 64 feats.
// 32 edge-slots/iter, 3-ballot counts, hoisted hpre.
__global__ void k_agg2(const unsigned int* __restrict__ entries,
                       const int* __restrict__ cursor,
                       const unsigned short* __restrict__ y,
                       const float* __restrict__ hpre,
                       const float* __restrict__ Wc, const float* __restrict__ bc,
                       float* __restrict__ out) {
  const int d = blockIdx.x * 4 + (threadIdx.x >> 6);
  const int lane = threadIdx.x & 63;
  int deg = cursor[d * CSTRIDE];
  if (deg > CAP) deg = CAP;
  unsigned int e = (lane < deg) ? entries[d * CAP + lane] : 0u;
  float sc = edge_scale(e, lane, deg);

  const int g = lane >> 3;   // edge slot within 32-slot pack
  const int l8 = lane & 7;   // feature slice: feats 8*l8 .. 8*l8+7

  const float4* hp = reinterpret_cast<const float4*>(hpre) + (size_t)d * 16 + l8 * 2;
  float4 h0 = hp[0];
  float4 h1 = hp[1];

  float a[8] = {};
  const int T = (deg + 31) >> 5;   // 32 edges per iteration (4x uint4 loads)
  for (int t = 0; t < T; ++t) {
    const int base = t * 32 + g;
    unsigned int e0 = __shfl(e, base, 64);       float s0 = __shfl(sc, base, 64);
    unsigned int e1 = __shfl(e, base + 8, 64);   float s1 = __shfl(sc, base + 8, 64);
    unsigned int e2 = __shfl(e, base + 16, 64);  float s2 = __shfl(sc, base + 16, 64);
    unsigned int e3 = __shfl(e, base + 24, 64);  float s3 = __shfl(sc, base + 24, 64);
    uint4 p0 = *reinterpret_cast<const uint4*>(
        y + (((size_t)(e0 & 0xffffu)) << 9) + (((e0 >> 16) & 7u) << 6) + (l8 << 3));
    uint4 p1 = *reinterpret_cast<const uint4*>(
        y + (((size_t)(e1 & 0xffffu)) << 9) + (((e1 >> 16) & 7u) << 6) + (l8 << 3));
    uint4 p2 = *reinterpret_cast<const uint4*>(
        y + (((size_t)(e2 & 0xffffu)) << 9) + (((e2 >> 16) & 7u) << 6) + (l8 << 3));
    uint4 p3 = *reinterpret_cast<const uint4*>(
        y + (((size_t)(e3 & 0xffffu)) << 9) + (((e3 >> 16) & 7u) << 6) + (l8 << 3));
    ACC8(p0, s0);
    ACC8(p1, s1);
    ACC8(p2, s2);
    ACC8(p3, s3);
  }
#pragma unroll
  for (int j = 0; j < 8; ++j) {
    a[j] += __shfl_xor(a[j], 8, 64);
    a[j] += __shfl_xor(a[j], 16, 64);
    a[j] += __shfl_xor(a[j], 32, 64);
  }
  float v0 = fmaxf(a[0] + h0.x, 0.f), v1 = fmaxf(a[1] + h0.y, 0.f);
  float v2 = fmaxf(a[2] + h0.z, 0.f), v3 = fmaxf(a[3] + h0.w, 0.f);
  float v4 = fmaxf(a[4] + h1.x, 0.f), v5 = fmaxf(a[5] + h1.y, 0.f);
  float v6 = fmaxf(a[6] + h1.z, 0.f), v7 = fmaxf(a[7] + h1.w, 0.f);
  const float4* wc4 = reinterpret_cast<const float4*>(Wc) + l8 * 4;
  float4 w0 = wc4[0], w1 = wc4[1], w2 = wc4[2], w3 = wc4[3];
  float p0 = v0 * w0.x + v1 * w0.z + v2 * w1.x + v3 * w1.z
           + v4 * w2.x + v5 * w2.z + v6 * w3.x + v7 * w3.z;
  float p1 = v0 * w0.y + v1 * w0.w + v2 * w1.y + v3 * w1.w
           + v4 * w2.y + v5 * w2.w + v6 * w3.y + v7 * w3.w;
  p0 += __shfl_xor(p0, 1, 64); p1 += __shfl_xor(p1, 1, 64);
  p0 += __shfl_xor(p0, 2, 64); p1 += __shfl_xor(p1, 2, 64);
  p0 += __shfl_xor(p0, 4, 64); p1 += __shfl_xor(p1, 4, 64);
  if (lane == 0) {
    out[d * 2 + 0] = p0 + bc[0];
    out[d * 2 + 1] = p1 + bc[1];
  }
}

extern "C" void kernel_launch(void* const* d_in, const int* in_sizes, int n_in,
                              void* d_out, int out_size, void* d_ws, size_t ws_size,
                              hipStream_t stream) {
  const float* x     = (const float*)d_in[0];
  const int*   ei    = (const int*)d_in[1];
  const int*   et    = (const int*)d_in[2];
  const float* W1    = (const float*)d_in[3];
  const float* root1 = (const float*)d_in[4];
  const float* b1    = (const float*)d_in[5];
  const float* W2    = (const float*)d_in[6];
  const float* root2 = (const float*)d_in[7];
  const float* b2    = (const float*)d_in[8];
  const float* Wc    = (const float*)d_in[9];
  const float* bc    = (const float*)d_in[10];
  const int* srcI = ei;        // edge_index[0]
  const int* dstI = ei + EE;   // edge_index[1]

  char* ws = (char*)d_ws;
  unsigned short* xb      = (unsigned short*)(ws);             // 12,800,000 B
  unsigned int*   hbf     = (unsigned int*)(ws);               // alias (xb dead after gemm1)
  unsigned short* B1T     = (unsigned short*)(ws + 12800000);  //    294,912 B
  unsigned short* B2T     = (unsigned short*)(ws + 13094912);  //    163,840 B
  int*            cursor  = (int*)(ws + 13258752);             //  3,200,000 B (50000 x 64B padded)
  unsigned int*   entries = (unsigned int*)(ws + 16458752);    //  9,600,000 B (50000*48*4)
  float*          hpre    = (float*)(ws + 26058752);           // 25,600,000 B (reused layer 2)
  unsigned short* y1      = (unsigned short*)(ws + 51658752);  // 102,400,000 B
  unsigned short* y2      = y1;                                // alias (y1 dead after agg1)
  // total: 154,058,752 B (<= previous 154,258,752 footprint)

  // prologue: conv + B1^T + B2^T + padded-cursor zero (one dispatch, no memset)
  const int PRO_N = CONV_N + B1_N + B2_N + NN;
  k_prologue<<<(PRO_N + 255) / 256, 256, 0, stream>>>(x, xb, W1, root1, B1T,
                                                      W2, root2, B2T, cursor);

  // layer 1 (fused): y1 = xb @ [W1_0..W1_7] (bf16), hpre = xb @ root1 + b1 (f32),
  // PLUS edge-list build on 2500 interleaved edge blocks (r8 geometry, padded cursor).
  k_gemm<true><<<dim3(NBG1 + NBE), 256, 0, stream>>>(xb, B1T, y1, hpre, b1,
                                                     NN, 1024, 128, 6,
                                                     srcI, dstI, et, cursor, entries);
  k_agg1<<<NN / 4, 256, 0, stream>>>(entries, cursor, y1, hpre, hbf);

  // layer 2: y2 = hbf @ [W2_0..W2_7] (bf16), hpre = hbf @ root2 + b2 (f32)
  k_gemm<false><<<dim3(391 * 2), 256, 0, stream>>>((const unsigned short*)hbf, B2T, y2, hpre, b2,
                                                   NN, 512, 64, 5,
                                                   nullptr, nullptr, nullptr, nullptr, nullptr);
  k_agg2<<<NN / 4, 256, 0, stream>>>(entries, cursor, y2, hpre, Wc, bc, (float*)d_out);
}